// Round 1
// baseline (295.225 us; speedup 1.0000x reference)
//
#include <hip/hip_runtime.h>
#include <hip/hip_bf16.h>
#include <math.h>

#define DEVI __device__ __forceinline__

typedef __attribute__((ext_vector_type(4))) float f32x4;
typedef __attribute__((ext_vector_type(8))) short bf16x8;

DEVI unsigned short f2bf(float f) {
  union { float f; unsigned int u; } v; v.f = f;
  return (unsigned short)((v.u + 0x7FFFu + ((v.u >> 16) & 1u)) >> 16);
}
DEVI float bf2f(unsigned short s) {
  union { unsigned int u; float f; } v; v.u = ((unsigned int)s) << 16; return v.f;
}
DEVI bf16x8 pack8(f32x4 a, f32x4 b) {
  bf16x8 r;
  r[0] = (short)f2bf(a[0]); r[1] = (short)f2bf(a[1]);
  r[2] = (short)f2bf(a[2]); r[3] = (short)f2bf(a[3]);
  r[4] = (short)f2bf(b[0]); r[5] = (short)f2bf(b[1]);
  r[6] = (short)f2bf(b[2]); r[7] = (short)f2bf(b[3]);
  return r;
}

// ---------------- weight transpose + bf16 convert (runs once per launch) ---
struct TJobs {
  const float* src[6];
  unsigned short* dst[6];
  int K[6];
  int base[6];
};

__global__ __launch_bounds__(256) void transpose_weights(TJobs J) {
  __shared__ float t[32][33];
  int tile = blockIdx.x;
  int job = 0;
  while (job < 5 && tile >= J.base[job + 1]) ++job;
  int tl = tile - J.base[job];
  int K = J.K[job];
  int tn = tl & 15;   // 512/32 = 16 n-tiles
  int tk = tl >> 4;
  int x = threadIdx.x & 31, y = threadIdx.x >> 5;
  const float* s = J.src[job];
  int k0 = tk * 32, n0 = tn * 32;
  for (int yy = y; yy < 32; yy += 8)
    t[yy][x] = s[(size_t)(k0 + yy) * 512 + n0 + x];
  __syncthreads();
  unsigned short* d = J.dst[job];
  for (int yy = y; yy < 32; yy += 8)
    d[(size_t)(n0 + yy) * K + k0 + x] = f2bf(t[x][yy]);
}

// ---------------- generic MFMA GEMM: C[M][512] = concatA @ B + bias --------
// A given as up to 4 segments of 512 columns each (row stride Astride).
// Bt is bf16 [512][K] (i.e. B transposed), so both operands are k-contiguous.
struct GemmJob {
  const float* Aseg[4];
  const unsigned short* Bt;
  const float* bias;
  float* C;
  int Astride, M, K, relu;
};
struct GemmBatch { GemmJob j[4]; };

__global__ __launch_bounds__(256) void gemm_kernel(GemmBatch batch) {
  GemmJob J = batch.j[blockIdx.z];
  int bm = blockIdx.y * 128, bn = blockIdx.x * 128;
  if (bm >= J.M) return;
  __shared__ unsigned short Al[128 * 64];
  __shared__ unsigned short Bl[128 * 64];
  int tid = threadIdx.x;
  int wave = tid >> 6, lane = tid & 63;
  int wr = (wave >> 1) * 64, wc = (wave & 1) * 64;
  int lrow = lane & 15, lq = lane >> 4;
  f32x4 acc[4][4] = {};

  int ar = tid >> 1;            // 128 rows, 2 threads/row
  int akb0 = (tid & 1) * 4;     // 4 kblocks-of-8 each
  int br_ = tid >> 3;           // B: 32 rows per pass
  int bc = tid & 7;             // 8 kblocks

  for (int k0 = 0; k0 < J.K; k0 += 64) {
    // stage A: f32 global -> bf16 LDS [row][64], kblock ADD-swizzled
    const float* Ap = J.Aseg[k0 >> 9] + (size_t)(bm + ar) * J.Astride + (k0 & 511) + akb0 * 8;
#pragma unroll
    for (int i = 0; i < 4; ++i) {
      f32x4 u = *(const f32x4*)(Ap + i * 8);
      f32x4 v = *(const f32x4*)(Ap + i * 8 + 4);
      int kb = akb0 + i;
      int skb = (kb + ar) & 7;
      *(bf16x8*)(&Al[ar * 64 + skb * 8]) = pack8(u, v);
    }
    // stage B: bf16 global (pre-transposed) -> bf16 LDS, same swizzle
#pragma unroll
    for (int p = 0; p < 4; ++p) {
      int r = br_ + p * 32;
      bf16x8 w = *(const bf16x8*)(J.Bt + (size_t)(bn + r) * J.K + k0 + bc * 8);
      int skb = (bc + r) & 7;
      *(bf16x8*)(&Bl[r * 64 + skb * 8]) = w;
    }
    __syncthreads();
#pragma unroll
    for (int kc = 0; kc < 2; ++kc) {
      bf16x8 af[4], bfr[4];
      int kb = kc * 4 + lq;
#pragma unroll
      for (int mi = 0; mi < 4; ++mi) {
        int row = wr + mi * 16 + lrow;
        af[mi] = *(const bf16x8*)(&Al[row * 64 + ((kb + row) & 7) * 8]);
      }
#pragma unroll
      for (int ni = 0; ni < 4; ++ni) {
        int row = wc + ni * 16 + lrow;
        bfr[ni] = *(const bf16x8*)(&Bl[row * 64 + ((kb + row) & 7) * 8]);
      }
#pragma unroll
      for (int mi = 0; mi < 4; ++mi)
#pragma unroll
        for (int ni = 0; ni < 4; ++ni)
          acc[mi][ni] = __builtin_amdgcn_mfma_f32_16x16x32_bf16(af[mi], bfr[ni], acc[mi][ni], 0, 0, 0);
    }
    __syncthreads();
  }
  // epilogue: C/D layout col=lane&15, row=(lane>>4)*4+reg
#pragma unroll
  for (int mi = 0; mi < 4; ++mi) {
#pragma unroll
    for (int ni = 0; ni < 4; ++ni) {
      int gm = bm + wr + mi * 16 + lq * 4;
      int gn = bn + wc + ni * 16 + lrow;
      float bv = J.bias[gn];
#pragma unroll
      for (int r = 0; r < 4; ++r) {
        float vv = acc[mi][ni][r] + bv;
        if (J.relu) vv = fmaxf(vv, 0.f);
        J.C[(size_t)(gm + r) * 512 + gn] = vv;
      }
    }
  }
}

// ---------------- scores + separable softmax ------------------------------
// ws[b,l,s] = softmax_s(cc * q . t_key[b,s]);  wt[b,l,t] = softmax_t(cc * q . s_key[b,t])
__global__ __launch_bounds__(256) void attn_scores(
    const float* __restrict__ q, const float* __restrict__ s_key,
    const float* __restrict__ t_key, float* __restrict__ Wsw,
    float* __restrict__ Wtw) {
  int b = blockIdx.x;
  int wave = threadIdx.x >> 6, lane = threadIdx.x & 63;
  int lrow = lane & 15, lq = lane >> 4;
  const float* qb = q + (size_t)b * 128 * 512;
  const float* keyp[2] = { t_key + (size_t)b * 36 * 512, s_key + (size_t)b * 36 * 512 };
  f32x4 acc[2][2][3] = {};   // [mat][mi][nfrag]
  for (int kc = 0; kc < 16; ++kc) {
    int k = kc * 32 + lq * 8;
    bf16x8 af[2];
#pragma unroll
    for (int mi = 0; mi < 2; ++mi) {
      const float* p = qb + (size_t)(wave * 32 + mi * 16 + lrow) * 512 + k;
      af[mi] = pack8(*(const f32x4*)p, *(const f32x4*)(p + 4));
    }
#pragma unroll
    for (int m = 0; m < 2; ++m) {
#pragma unroll
      for (int nf = 0; nf < 3; ++nf) {
        int n = nf * 16 + lrow; if (n > 35) n = 35;   // clamp (masked later)
        const float* p = keyp[m] + (size_t)n * 512 + k;
        bf16x8 bf_ = pack8(*(const f32x4*)p, *(const f32x4*)(p + 4));
#pragma unroll
        for (int mi = 0; mi < 2; ++mi)
          acc[m][mi][nf] = __builtin_amdgcn_mfma_f32_16x16x32_bf16(af[mi], bf_, acc[m][mi][nf], 0, 0, 0);
      }
    }
  }
  const float ccs = 0.022097086912079608f;   // 0.5 / sqrt(512)
#pragma unroll
  for (int m = 0; m < 2; ++m) {
    float* W = (m == 0 ? Wsw : Wtw);
#pragma unroll
    for (int mi = 0; mi < 2; ++mi) {
      float ex[3][4];
#pragma unroll
      for (int r = 0; r < 4; ++r) {
        float a0 = acc[m][mi][0][r] * ccs;
        float a1 = acc[m][mi][1][r] * ccs;
        float a2 = (lrow < 4) ? acc[m][mi][2][r] * ccs : -1e30f;
        float mx = fmaxf(fmaxf(a0, a1), a2);
        for (int s = 1; s < 16; s <<= 1) mx = fmaxf(mx, __shfl_xor(mx, s));
        float e0 = __expf(a0 - mx), e1 = __expf(a1 - mx);
        float e2 = (lrow < 4) ? __expf(a2 - mx) : 0.f;
        float sum = e0 + e1 + e2;
        for (int s = 1; s < 16; s <<= 1) sum += __shfl_xor(sum, s);
        float inv = 1.f / sum;
        ex[0][r] = e0 * inv; ex[1][r] = e1 * inv; ex[2][r] = e2 * inv;
      }
      size_t rowbase = (size_t)b * 128 + wave * 32 + mi * 16;
#pragma unroll
      for (int nf = 0; nf < 3; ++nf) {
        int col = nf * 16 + lrow;
        if (col < 36) {
#pragma unroll
          for (int r = 0; r < 4; ++r)
            W[(rowbase + lq * 4 + r) * 36 + col] = ex[nf][r];
        }
      }
    }
  }
}

// ---------------- ctx: ctx[l][h] = sum_j w[l][j] * value[j][h]  (K=36) -----
__global__ __launch_bounds__(256) void attn_ctx(
    const float* __restrict__ Wsw, const float* __restrict__ Wtw,
    const float* __restrict__ s_value, const float* __restrict__ t_value,
    float* __restrict__ s_ctx, float* __restrict__ t_ctx) {
  __shared__ unsigned short vl[36 * 512];
  __shared__ float wl[32 * 36];
  int l0 = blockIdx.x * 32, mat = blockIdx.y, b = blockIdx.z;
  const float* V = (mat ? t_value : s_value) + (size_t)b * 36 * 512;
  const float* W = (mat ? Wtw : Wsw) + ((size_t)b * 128 + l0) * 36;
  float* C = (mat ? t_ctx : s_ctx) + ((size_t)b * 128 + l0) * 512;
  int tid = threadIdx.x;
  for (int i = tid; i < 36 * 512 / 4; i += 256) {
    f32x4 u = *(const f32x4*)(V + i * 4);
    unsigned short* d = &vl[i * 4];
    d[0] = f2bf(u[0]); d[1] = f2bf(u[1]); d[2] = f2bf(u[2]); d[3] = f2bf(u[3]);
  }
  for (int i = tid; i < 32 * 36; i += 256) wl[i] = W[i];
  __syncthreads();
  int h0 = tid * 2;
  for (int l = 0; l < 32; ++l) {
    float a0 = 0.f, a1 = 0.f;
    const float* wrow = &wl[l * 36];
#pragma unroll 4
    for (int j = 0; j < 36; ++j) {
      float w = wrow[j];
      unsigned int pv = *(const unsigned int*)(&vl[j * 512 + h0]);
      a0 += w * bf2f((unsigned short)(pv & 0xffffu));
      a1 += w * bf2f((unsigned short)(pv >> 16));
    }
    C[(size_t)l * 512 + h0] = a0;
    C[(size_t)l * 512 + h0 + 1] = a1;
  }
}

// ---------------------------------------------------------------------------
extern "C" void kernel_launch(void* const* d_in, const int* in_sizes, int n_in,
                              void* d_out, int out_size, void* d_ws, size_t ws_size,
                              hipStream_t stream) {
  (void)in_sizes; (void)n_in; (void)out_size; (void)ws_size;
  const float* query = (const float*)d_in[0];
  const float* src   = (const float*)d_in[1];
  const float* trg   = (const float*)d_in[2];
  const float* Wq  = (const float*)d_in[3];  const float* bq  = (const float*)d_in[4];
  const float* Wsk = (const float*)d_in[5];  const float* bs  = (const float*)d_in[6];
  const float* Wtk = (const float*)d_in[7];  const float* bt  = (const float*)d_in[8];
  const float* Wsv = (const float*)d_in[9];  const float* bsv = (const float*)d_in[10];
  const float* Wtv = (const float*)d_in[11]; const float* btv = (const float*)d_in[12];
  const float* Wo  = (const float*)d_in[13]; const float* bo  = (const float*)d_in[14];

  // workspace layout (bf16 transposed weights, then f32 activations) ~46 MB
  unsigned short* WqT  = (unsigned short*)d_ws;       // 512*512
  unsigned short* WsT  = WqT  + 512 * 512;            // 512*2048 each
  unsigned short* WtT  = WsT  + 512 * 2048;
  unsigned short* WsvT = WtT  + 512 * 2048;
  unsigned short* WtvT = WsvT + 512 * 2048;
  unsigned short* WoT  = WtvT + 512 * 2048;           // 512*1536
  float* fbase  = (float*)(WoT + 512 * 1536);
  float* qh     = fbase;                // 4096*512
  float* s_key  = qh     + 4096 * 512;  // 1152*512
  float* t_keyb = s_key  + 1152 * 512;
  float* s_val  = t_keyb + 1152 * 512;
  float* t_val  = s_val  + 1152 * 512;
  float* Wsw    = t_val  + 1152 * 512;  // 4096*36
  float* Wtw    = Wsw    + 4096 * 36;
  float* s_ctx  = Wtw    + 4096 * 36;   // 4096*512
  float* t_ctx  = s_ctx  + 4096 * 512;
  float* out    = (float*)d_out;

  // 1. transpose + convert all weights to bf16 [N][K]
  TJobs tj;
  tj.src[0] = Wq;  tj.dst[0] = WqT;  tj.K[0] = 512;
  tj.src[1] = Wsk; tj.dst[1] = WsT;  tj.K[1] = 2048;
  tj.src[2] = Wtk; tj.dst[2] = WtT;  tj.K[2] = 2048;
  tj.src[3] = Wsv; tj.dst[3] = WsvT; tj.K[3] = 2048;
  tj.src[4] = Wtv; tj.dst[4] = WtvT; tj.K[4] = 2048;
  tj.src[5] = Wo;  tj.dst[5] = WoT;  tj.K[5] = 1536;
  int base = 0;
  for (int i = 0; i < 6; ++i) { tj.base[i] = base; base += (tj.K[i] / 32) * 16; }
  transpose_weights<<<base, 256, 0, stream>>>(tj);

  // 2. four projection GEMMs, batched over blockIdx.z
  GemmBatch pb;
  {
    const float* Aarr[4] = { src, trg, src, trg };
    const unsigned short* Barr[4] = { WsT, WtT, WsvT, WtvT };
    const float* biasArr[4] = { bs, bt, bsv, btv };
    float* Carr[4] = { s_key, t_keyb, s_val, t_val };
    for (int i = 0; i < 4; ++i) {
      for (int s2 = 0; s2 < 4; ++s2) pb.j[i].Aseg[s2] = Aarr[i] + s2 * 512;
      pb.j[i].Bt = Barr[i]; pb.j[i].bias = biasArr[i]; pb.j[i].C = Carr[i];
      pb.j[i].Astride = 2048; pb.j[i].M = 1152; pb.j[i].K = 2048; pb.j[i].relu = 0;
    }
  }
  gemm_kernel<<<dim3(4, 9, 4), 256, 0, stream>>>(pb);

  // 3. q projection
  GemmBatch qb_;
  for (int s2 = 0; s2 < 4; ++s2) qb_.j[0].Aseg[s2] = query;
  qb_.j[0].Bt = WqT; qb_.j[0].bias = bq; qb_.j[0].C = qh;
  qb_.j[0].Astride = 512; qb_.j[0].M = 4096; qb_.j[0].K = 512; qb_.j[0].relu = 0;
  qb_.j[1] = qb_.j[0]; qb_.j[2] = qb_.j[0]; qb_.j[3] = qb_.j[0];
  gemm_kernel<<<dim3(4, 32, 1), 256, 0, stream>>>(qb_);

  // 4. separable scores + softmax
  attn_scores<<<32, 256, 0, stream>>>(qh, s_key, t_keyb, Wsw, Wtw);

  // 5. context weighted sums
  attn_ctx<<<dim3(4, 2, 32), 256, 0, stream>>>(Wsw, Wtw, s_val, t_val, s_ctx, t_ctx);

  // 6. output GEMM on virtual concat [query | s_ctx | t_ctx], bias + ReLU
  GemmBatch ob;
  ob.j[0].Aseg[0] = query; ob.j[0].Aseg[1] = s_ctx;
  ob.j[0].Aseg[2] = t_ctx; ob.j[0].Aseg[3] = t_ctx;
  ob.j[0].Bt = WoT; ob.j[0].bias = bo; ob.j[0].C = out;
  ob.j[0].Astride = 512; ob.j[0].M = 4096; ob.j[0].K = 1536; ob.j[0].relu = 1;
  ob.j[1] = ob.j[0]; ob.j[2] = ob.j[0]; ob.j[3] = ob.j[0];
  gemm_kernel<<<dim3(4, 32, 1), 256, 0, stream>>>(ob);
}

// Round 2
// 152.029 us; speedup vs baseline: 1.9419x; 1.9419x over previous
//
#include <hip/hip_runtime.h>
#include <hip/hip_bf16.h>
#include <math.h>

#define DEVI __device__ __forceinline__

typedef __attribute__((ext_vector_type(4))) float f32x4;
typedef __attribute__((ext_vector_type(8))) short bf16x8;

DEVI unsigned short f2bf(float f) {
  union { float f; unsigned int u; } v; v.f = f;
  return (unsigned short)((v.u + 0x7FFFu + ((v.u >> 16) & 1u)) >> 16);
}
DEVI float bf2f(unsigned short s) {
  union { unsigned int u; float f; } v; v.u = ((unsigned int)s) << 16; return v.f;
}
DEVI bf16x8 pack8(f32x4 a, f32x4 b) {
  bf16x8 r;
  r[0] = (short)f2bf(a[0]); r[1] = (short)f2bf(a[1]);
  r[2] = (short)f2bf(a[2]); r[3] = (short)f2bf(a[3]);
  r[4] = (short)f2bf(b[0]); r[5] = (short)f2bf(b[1]);
  r[6] = (short)f2bf(b[2]); r[7] = (short)f2bf(b[3]);
  return r;
}
DEVI void gload16(const unsigned short* g, unsigned short* l) {
  __builtin_amdgcn_global_load_lds(
      (const __attribute__((address_space(1))) unsigned int*)g,
      (__attribute__((address_space(3))) unsigned int*)l, 16, 0, 0);
}

// ---------------- weight transpose + bf16 convert + k-block pre-swizzle ----
// dst logical layout: [N][K] k-contiguous, but within each aligned 64-elem
// k-group, the 8-elem kblock kb of row n is stored at position ((kb+n)&7).
// gemm64 then stages B with linear global_load_lds and reads with the same
// ADD-swizzle -> bank-conflict-free and DMA-direct.
struct TJobs {
  const float* src[6];
  unsigned short* dst[6];
  int K[6];
  int base[6];
};

__global__ __launch_bounds__(256) void transpose_weights(TJobs J) {
  __shared__ float t[32][33];
  int tile = blockIdx.x;
  int job = 0;
  while (job < 5 && tile >= J.base[job + 1]) ++job;
  int tl = tile - J.base[job];
  int K = J.K[job];
  int tn = tl & 15;   // 512/32 = 16 n-tiles
  int tk = tl >> 4;
  int x = threadIdx.x & 31, y = threadIdx.x >> 5;
  const float* s = J.src[job];
  int k0 = tk * 32, n0 = tn * 32;
  for (int yy = y; yy < 32; yy += 8)
    t[yy][x] = s[(size_t)(k0 + yy) * 512 + n0 + x];
  __syncthreads();
  unsigned short* d = J.dst[job];
  int k = k0 + x;
  int kg = k >> 6, kb = (k >> 3) & 7, ko = k & 7;
  for (int yy = y; yy < 32; yy += 8) {
    int n = n0 + yy;
    int kswz = (kg << 6) | (((kb + n) & 7) << 3) | ko;
    d[(size_t)n * K + kswz] = f2bf(t[x][yy]);
  }
}

// ---------------- 64x64-tile MFMA GEMM, double-buffered, 1 barrier/K-step --
// C[M][512] = concat(A0|A1|A2) @ B + bias, optional relu.
// A segments: f32, row stride Astride, Kseg = 64<<lgSteps columns each.
// Bt: bf16 [512][Ktot], pre-swizzled per 64-group (see transpose_weights).
struct GJob {
  const float* A0; const float* A1; const float* A2;
  const unsigned short* Bt;
  const float* bias;
  float* C;
  int Astride, Ktot, lgSteps, relu, tileBase;
};
struct GBatch { GJob j[6]; int njobs; };

__global__ __launch_bounds__(256) void gemm64(GBatch batch) {
  int gt = blockIdx.x;
  int job = 0;
#pragma unroll
  for (int i = 1; i < 6; ++i)
    if (i < batch.njobs && gt >= batch.j[i].tileBase) job = i;
  GJob J = batch.j[job];
  int tl = gt - J.tileBase;
  int bm = (tl >> 3) * 64, bn = (tl & 7) * 64;

  __shared__ unsigned short La[2][64 * 64];
  __shared__ unsigned short Lb[2][64 * 64];

  int tid = threadIdx.x;
  int wave = tid >> 6, lane = tid & 63;
  int lrow = lane & 15, lq = lane >> 4;
  int wr = (wave >> 1) * 32, wc = (wave & 1) * 32;
  f32x4 acc[2][2] = {};

  int row_a = tid >> 2, kq = tid & 3;        // A: 4 threads/row, 16 f32 each
  int kmask = (1 << J.lgSteps) - 1;
  int nt = J.Ktot >> 6;

  // ---- helpers as lambdas (compile-time inlined) ----
  auto a_addr = [&](int t) -> const float* {
    int seg = t >> J.lgSteps;
    const float* Ab = (seg == 0) ? J.A0 : ((seg == 1) ? J.A1 : J.A2);
    int kkA = (t & kmask) << 6;
    return Ab + (size_t)(bm + row_a) * J.Astride + kkA + kq * 16;
  };
  auto b_stage = [&](int t, int buf) {
    size_t kof = (size_t)t * 64;
    int s0 = tid, s1 = tid + 256;
    const unsigned short* g0 = J.Bt + (size_t)(bn + (s0 >> 3)) * J.Ktot + kof + (s0 & 7) * 8;
    const unsigned short* g1 = J.Bt + (size_t)(bn + (s1 >> 3)) * J.Ktot + kof + (s1 & 7) * 8;
    gload16(g0, &Lb[buf][(wave * 64) * 8]);
    gload16(g1, &Lb[buf][(256 + wave * 64) * 8]);
  };
  auto a_write = [&](f32x4 a0, f32x4 a1, f32x4 a2, f32x4 a3, int buf) {
    bf16x8 w0 = pack8(a0, a1), w1 = pack8(a2, a3);
    int kb0 = kq * 2;
    *(bf16x8*)&La[buf][row_a * 64 + ((kb0 + row_a) & 7) * 8] = w0;
    *(bf16x8*)&La[buf][row_a * 64 + ((kb0 + 1 + row_a) & 7) * 8] = w1;
  };

  // ---- prologue: stage tile 0 ----
  {
    b_stage(0, 0);
    const float* Ap = a_addr(0);
    f32x4 a0 = *(const f32x4*)(Ap);
    f32x4 a1 = *(const f32x4*)(Ap + 4);
    f32x4 a2 = *(const f32x4*)(Ap + 8);
    f32x4 a3 = *(const f32x4*)(Ap + 12);
    a_write(a0, a1, a2, a3, 0);
  }
  __syncthreads();

  int cur = 0;
  for (int t = 0; t < nt; ++t) {
    f32x4 a0, a1, a2, a3;
    bool pf = (t + 1 < nt);
    if (pf) {
      b_stage(t + 1, cur ^ 1);                 // async DMA into other buffer
      const float* Ap = a_addr(t + 1);
      a0 = *(const f32x4*)(Ap);
      a1 = *(const f32x4*)(Ap + 4);
      a2 = *(const f32x4*)(Ap + 8);
      a3 = *(const f32x4*)(Ap + 12);
    }
    // ---- compute from current buffers ----
#pragma unroll
    for (int kc = 0; kc < 2; ++kc) {
      int kb = kc * 4 + lq;
      bf16x8 af[2], bf_[2];
#pragma unroll
      for (int mi = 0; mi < 2; ++mi) {
        int r = wr + mi * 16 + lrow;
        af[mi] = *(const bf16x8*)&La[cur][r * 64 + ((kb + r) & 7) * 8];
      }
#pragma unroll
      for (int ni = 0; ni < 2; ++ni) {
        int r = wc + ni * 16 + lrow;
        bf_[ni] = *(const bf16x8*)&Lb[cur][r * 64 + ((kb + r) & 7) * 8];
      }
#pragma unroll
      for (int mi = 0; mi < 2; ++mi)
#pragma unroll
        for (int ni = 0; ni < 2; ++ni)
          acc[mi][ni] = __builtin_amdgcn_mfma_f32_16x16x32_bf16(af[mi], bf_[ni], acc[mi][ni], 0, 0, 0);
    }
    if (pf) a_write(a0, a1, a2, a3, cur ^ 1);  // waits only its own vmcnt
    __syncthreads();                            // drains DMA + publishes LDS
    cur ^= 1;
  }

  // ---- epilogue: C/D layout col=lane&15, row=lq*4+reg ----
#pragma unroll
  for (int mi = 0; mi < 2; ++mi) {
#pragma unroll
    for (int ni = 0; ni < 2; ++ni) {
      int gn = bn + wc + ni * 16 + lrow;
      float bv = J.bias[gn];
      int gm0 = bm + wr + mi * 16 + lq * 4;
#pragma unroll
      for (int r = 0; r < 4; ++r) {
        float vv = acc[mi][ni][r] + bv;
        if (J.relu) vv = fmaxf(vv, 0.f);
        J.C[(size_t)(gm0 + r) * 512 + gn] = vv;
      }
    }
  }
}

// ---------------- scores + separable softmax ------------------------------
// ws[b,l,s] = softmax_s(cc * q . t_key[b,s]);  wt[b,l,t] = softmax_t(cc * q . s_key[b,t])
__global__ __launch_bounds__(256) void attn_scores(
    const float* __restrict__ q, const float* __restrict__ s_key,
    const float* __restrict__ t_key, float* __restrict__ Wsw,
    float* __restrict__ Wtw) {
  int b = blockIdx.x;
  int wave = threadIdx.x >> 6, lane = threadIdx.x & 63;
  int lrow = lane & 15, lq = lane >> 4;
  const float* qb = q + (size_t)b * 128 * 512;
  const float* keyp[2] = { t_key + (size_t)b * 36 * 512, s_key + (size_t)b * 36 * 512 };
  f32x4 acc[2][2][3] = {};   // [mat][mi][nfrag]
  for (int kc = 0; kc < 16; ++kc) {
    int k = kc * 32 + lq * 8;
    bf16x8 af[2];
#pragma unroll
    for (int mi = 0; mi < 2; ++mi) {
      const float* p = qb + (size_t)(wave * 32 + mi * 16 + lrow) * 512 + k;
      af[mi] = pack8(*(const f32x4*)p, *(const f32x4*)(p + 4));
    }
#pragma unroll
    for (int m = 0; m < 2; ++m) {
#pragma unroll
      for (int nf = 0; nf < 3; ++nf) {
        int n = nf * 16 + lrow; if (n > 35) n = 35;   // clamp (masked later)
        const float* p = keyp[m] + (size_t)n * 512 + k;
        bf16x8 bf_ = pack8(*(const f32x4*)p, *(const f32x4*)(p + 4));
#pragma unroll
        for (int mi = 0; mi < 2; ++mi)
          acc[m][mi][nf] = __builtin_amdgcn_mfma_f32_16x16x32_bf16(af[mi], bf_, acc[m][mi][nf], 0, 0, 0);
      }
    }
  }
  const float ccs = 0.022097086912079608f;   // 0.5 / sqrt(512)
#pragma unroll
  for (int m = 0; m < 2; ++m) {
    float* W = (m == 0 ? Wsw : Wtw);
#pragma unroll
    for (int mi = 0; mi < 2; ++mi) {
      float ex[3][4];
#pragma unroll
      for (int r = 0; r < 4; ++r) {
        float a0 = acc[m][mi][0][r] * ccs;
        float a1 = acc[m][mi][1][r] * ccs;
        float a2 = (lrow < 4) ? acc[m][mi][2][r] * ccs : -1e30f;
        float mx = fmaxf(fmaxf(a0, a1), a2);
        for (int s = 1; s < 16; s <<= 1) mx = fmaxf(mx, __shfl_xor(mx, s));
        float e0 = __expf(a0 - mx), e1 = __expf(a1 - mx);
        float e2 = (lrow < 4) ? __expf(a2 - mx) : 0.f;
        float sum = e0 + e1 + e2;
        for (int s = 1; s < 16; s <<= 1) sum += __shfl_xor(sum, s);
        float inv = 1.f / sum;
        ex[0][r] = e0 * inv; ex[1][r] = e1 * inv; ex[2][r] = e2 * inv;
      }
      size_t rowbase = (size_t)b * 128 + wave * 32 + mi * 16;
#pragma unroll
      for (int nf = 0; nf < 3; ++nf) {
        int col = nf * 16 + lrow;
        if (col < 36) {
#pragma unroll
          for (int r = 0; r < 4; ++r)
            W[(rowbase + lq * 4 + r) * 36 + col] = ex[nf][r];
        }
      }
    }
  }
}

// ---------------- ctx: ctx[l][h] = sum_j w[l][j] * value[j][h]  (K=36) -----
__global__ __launch_bounds__(256) void attn_ctx(
    const float* __restrict__ Wsw, const float* __restrict__ Wtw,
    const float* __restrict__ s_value, const float* __restrict__ t_value,
    float* __restrict__ s_ctx, float* __restrict__ t_ctx) {
  __shared__ unsigned short vl[36 * 512];
  __shared__ float wl[32 * 36];
  int l0 = blockIdx.x * 32, mat = blockIdx.y, b = blockIdx.z;
  const float* V = (mat ? t_value : s_value) + (size_t)b * 36 * 512;
  const float* W = (mat ? Wtw : Wsw) + ((size_t)b * 128 + l0) * 36;
  float* C = (mat ? t_ctx : s_ctx) + ((size_t)b * 128 + l0) * 512;
  int tid = threadIdx.x;
  for (int i = tid; i < 36 * 512 / 4; i += 256) {
    f32x4 u = *(const f32x4*)(V + i * 4);
    unsigned short* d = &vl[i * 4];
    d[0] = f2bf(u[0]); d[1] = f2bf(u[1]); d[2] = f2bf(u[2]); d[3] = f2bf(u[3]);
  }
  for (int i = tid; i < 32 * 36; i += 256) wl[i] = W[i];
  __syncthreads();
  int h0 = tid * 2;
  for (int l = 0; l < 32; ++l) {
    float a0 = 0.f, a1 = 0.f;
    const float* wrow = &wl[l * 36];
#pragma unroll 4
    for (int j = 0; j < 36; ++j) {
      float w = wrow[j];
      unsigned int pv = *(const unsigned int*)(&vl[j * 512 + h0]);
      a0 += w * bf2f((unsigned short)(pv & 0xffffu));
      a1 += w * bf2f((unsigned short)(pv >> 16));
    }
    C[(size_t)l * 512 + h0] = a0;
    C[(size_t)l * 512 + h0 + 1] = a1;
  }
}

// ---------------------------------------------------------------------------
extern "C" void kernel_launch(void* const* d_in, const int* in_sizes, int n_in,
                              void* d_out, int out_size, void* d_ws, size_t ws_size,
                              hipStream_t stream) {
  (void)in_sizes; (void)n_in; (void)out_size; (void)ws_size;
  const float* query = (const float*)d_in[0];
  const float* src   = (const float*)d_in[1];
  const float* trg   = (const float*)d_in[2];
  const float* Wq  = (const float*)d_in[3];  const float* bq  = (const float*)d_in[4];
  const float* Wsk = (const float*)d_in[5];  const float* bs  = (const float*)d_in[6];
  const float* Wtk = (const float*)d_in[7];  const float* bt  = (const float*)d_in[8];
  const float* Wsv = (const float*)d_in[9];  const float* bsv = (const float*)d_in[10];
  const float* Wtv = (const float*)d_in[11]; const float* btv = (const float*)d_in[12];
  const float* Wo  = (const float*)d_in[13]; const float* bo  = (const float*)d_in[14];

  // workspace layout (bf16 transposed weights, then f32 activations) ~46 MB
  unsigned short* WqT  = (unsigned short*)d_ws;       // 512*512
  unsigned short* WsT  = WqT  + 512 * 512;            // 512*2048 each
  unsigned short* WtT  = WsT  + 512 * 2048;
  unsigned short* WsvT = WtT  + 512 * 2048;
  unsigned short* WtvT = WsvT + 512 * 2048;
  unsigned short* WoT  = WtvT + 512 * 2048;           // 512*1536
  float* fbase  = (float*)(WoT + 512 * 1536);
  float* qh     = fbase;                // 4096*512
  float* s_key  = qh     + 4096 * 512;  // 1152*512
  float* t_keyb = s_key  + 1152 * 512;
  float* s_val  = t_keyb + 1152 * 512;
  float* t_val  = s_val  + 1152 * 512;
  float* Wsw    = t_val  + 1152 * 512;  // 4096*36
  float* Wtw    = Wsw    + 4096 * 36;
  float* s_ctx  = Wtw    + 4096 * 36;   // 4096*512
  float* t_ctx  = s_ctx  + 4096 * 512;
  float* out    = (float*)d_out;

  // 1. transpose + convert all weights to bf16 [N][K], pre-swizzled
  TJobs tj;
  tj.src[0] = Wq;  tj.dst[0] = WqT;  tj.K[0] = 512;
  tj.src[1] = Wsk; tj.dst[1] = WsT;  tj.K[1] = 2048;
  tj.src[2] = Wtk; tj.dst[2] = WtT;  tj.K[2] = 2048;
  tj.src[3] = Wsv; tj.dst[3] = WsvT; tj.K[3] = 2048;
  tj.src[4] = Wtv; tj.dst[4] = WtvT; tj.K[4] = 2048;
  tj.src[5] = Wo;  tj.dst[5] = WoT;  tj.K[5] = 1536;
  int tbase = 0;
  for (int i = 0; i < 6; ++i) { tj.base[i] = tbase; tbase += (tj.K[i] / 32) * 16; }
  transpose_weights<<<tbase, 256, 0, stream>>>(tj);

  // 2. merged dispatch: 4 projection GEMMs + q GEMM (1088 blocks)
  GBatch pb;
  {
    const float* Aarr[5] = { src, trg, src, trg, query };
    const unsigned short* Barr[5] = { WsT, WtT, WsvT, WtvT, WqT };
    const float* biasArr[5] = { bs, bt, bsv, btv, bq };
    float* Carr[5] = { s_key, t_keyb, s_val, t_val, qh };
    int base = 0;
    for (int i = 0; i < 5; ++i) {
      GJob& j = pb.j[i];
      j.A0 = Aarr[i]; j.A1 = Aarr[i]; j.A2 = Aarr[i];
      j.Bt = Barr[i]; j.bias = biasArr[i]; j.C = Carr[i];
      if (i < 4) { j.Astride = 2048; j.Ktot = 2048; j.lgSteps = 5; }   // 32 steps
      else       { j.Astride = 512;  j.Ktot = 512;  j.lgSteps = 3; }   // 8 steps
      j.relu = 0;
      j.tileBase = base;
      base += ((i < 4 ? 1152 : 4096) / 64) * 8;
    }
    pb.j[5] = pb.j[4]; pb.j[5].tileBase = 0x7fffffff;
    pb.njobs = 5;
    gemm64<<<base, 256, 0, stream>>>(pb);
  }

  // 3. separable scores + softmax
  attn_scores<<<32, 256, 0, stream>>>(qh, s_key, t_keyb, Wsw, Wtw);

  // 4. context weighted sums
  attn_ctx<<<dim3(4, 2, 32), 256, 0, stream>>>(Wsw, Wtw, s_val, t_val, s_ctx, t_ctx);

  // 5. output GEMM on virtual concat [query | s_ctx | t_ctx], bias + ReLU
  {
    GBatch ob;
    GJob& j = ob.j[0];
    j.A0 = query; j.A1 = s_ctx; j.A2 = t_ctx;
    j.Bt = WoT; j.bias = bo; j.C = out;
    j.Astride = 512; j.Ktot = 1536; j.lgSteps = 3;   // 3 segs x 8 steps
    j.relu = 1; j.tileBase = 0;
    for (int i = 1; i < 6; ++i) { ob.j[i] = j; ob.j[i].tileBase = 0x7fffffff; }
    ob.njobs = 1;
    gemm64<<<(4096 / 64) * 8, 256, 0, stream>>>(ob);
  }
}

// Round 3
// 108.767 us; speedup vs baseline: 2.7143x; 1.3978x over previous
//
#include <hip/hip_runtime.h>
#include <hip/hip_bf16.h>
#include <math.h>

#define DEVI __device__ __forceinline__

typedef __attribute__((ext_vector_type(4))) float f32x4;
typedef __attribute__((ext_vector_type(8))) short bf16x8;

DEVI unsigned short f2bf(float f) {
  union { float f; unsigned int u; } v; v.f = f;
  return (unsigned short)((v.u + 0x7FFFu + ((v.u >> 16) & 1u)) >> 16);
}
DEVI float bf2f(unsigned short s) {
  union { unsigned int u; float f; } v; v.u = ((unsigned int)s) << 16; return v.f;
}
DEVI bf16x8 pack8(f32x4 a, f32x4 b) {
  bf16x8 r;
  r[0] = (short)f2bf(a[0]); r[1] = (short)f2bf(a[1]);
  r[2] = (short)f2bf(a[2]); r[3] = (short)f2bf(a[3]);
  r[4] = (short)f2bf(b[0]); r[5] = (short)f2bf(b[1]);
  r[6] = (short)f2bf(b[2]); r[7] = (short)f2bf(b[3]);
  return r;
}
DEVI void gload16(const unsigned short* g, unsigned short* l) {
  __builtin_amdgcn_global_load_lds(
      (const __attribute__((address_space(1))) unsigned int*)g,
      (__attribute__((address_space(3))) unsigned int*)l, 16, 0, 0);
}

// ==== prep: weights f32[K][512] -> bf16 [512][K] swz ; acts f32[M][K] -> bf16 [M][K] swz
// swizzle: within each 64-elem k-group, kblock kb of row n stored at ((kb+n)&7).
struct PrepJobs {
  const float* src[9];
  unsigned short* dst[9];
  int K[9];
  int base[9];
  int type[9];   // 0 = weight transpose, 1 = activation convert
};

__global__ __launch_bounds__(256) void prep(PrepJobs J) {
  __shared__ float t[32][33];
  int tile = blockIdx.x;
  int job = 0;
  while (job < 8 && tile >= J.base[job + 1]) ++job;
  int tl = tile - J.base[job];
  int K = J.K[job];
  if (J.type[job] == 0) {
    int tn = tl & 15, tk = tl >> 4;   // 512/32 = 16 n-tiles
    int x = threadIdx.x & 31, y = threadIdx.x >> 5;
    const float* s = J.src[job];
    int k0 = tk * 32, n0 = tn * 32;
    for (int yy = y; yy < 32; yy += 8)
      t[yy][x] = s[(size_t)(k0 + yy) * 512 + n0 + x];
    __syncthreads();
    unsigned short* d = J.dst[job];
    int k = k0 + x;
    int kg = k >> 6, kb = (k >> 3) & 7, ko = k & 7;
    for (int yy = y; yy < 32; yy += 8) {
      int n = n0 + yy;
      int kswz = (kg << 6) | (((kb + n) & 7) << 3) | ko;
      d[(size_t)n * K + kswz] = f2bf(t[x][yy]);
    }
  } else {
    int nk = K >> 6;
    int rt = tl / nk;
    int r0 = rt * 64, k0 = (tl - rt * nk) * 64;
    int r = threadIdx.x >> 2, kq = threadIdx.x & 3;
    int row = r0 + r;
    const float* s = J.src[job] + (size_t)row * K + k0 + kq * 16;
    f32x4 a0 = *(const f32x4*)s;
    f32x4 a1 = *(const f32x4*)(s + 4);
    f32x4 a2 = *(const f32x4*)(s + 8);
    f32x4 a3 = *(const f32x4*)(s + 12);
    unsigned short* d = J.dst[job] + (size_t)row * K + k0;
    int kb0 = kq * 2;
    *(bf16x8*)(d + ((kb0 + row) & 7) * 8) = pack8(a0, a1);
    *(bf16x8*)(d + ((kb0 + 1 + row) & 7) * 8) = pack8(a2, a3);
  }
}

// ==== 128x128-tile all-DMA MFMA GEMM, double-buffered, 1 barrier/K-step ====
// C[M][512] = concat(A0|A1|A2) @ B + bias. A segs: bf16 swz, Kseg = 64<<lgSteps.
// Bt: bf16 [512][Ktot] swz. Output: bf16 (Cb) or f32+relu (Cf).
struct GJob {
  const unsigned short* A0; const unsigned short* A1; const unsigned short* A2;
  const unsigned short* Bt;
  const float* bias;
  unsigned short* Cb;
  float* Cf;
  int Astride, Ktot, lgSteps, tileBase;
};
struct GBatch { GJob j[5]; int njobs; };

__global__ __launch_bounds__(256) void gemm128(GBatch batch) {
  // XCD-aware swizzle (grid divisible by 8)
  int cpx = gridDim.x >> 3;
  int gt = (blockIdx.x & 7) * cpx + (blockIdx.x >> 3);
  int job = 0;
#pragma unroll
  for (int i = 1; i < 5; ++i)
    if (i < batch.njobs && gt >= batch.j[i].tileBase) job = i;
  GJob J = batch.j[job];
  int tl = gt - J.tileBase;
  int bm = (tl >> 2) * 128, bn = (tl & 3) * 128;   // N=512 -> 4 n-tiles

  __shared__ unsigned short La[2][128 * 64];
  __shared__ unsigned short Lb[2][128 * 64];

  int tid = threadIdx.x;
  int wave = tid >> 6, lane = tid & 63;
  int lrow = lane & 15, lq = lane >> 4;
  int wr = (wave >> 1) * 64, wc = (wave & 1) * 64;
  f32x4 acc[4][4] = {};

  int kmask = (1 << J.lgSteps) - 1;
  int nt = J.Ktot >> 6;

  auto stage = [&](const unsigned short* G, int gstride, unsigned short* L) {
#pragma unroll
    for (int p = 0; p < 4; ++p) {
      int s = p * 256 + tid;
      gload16(G + (size_t)(s >> 3) * gstride + (s & 7) * 8,
              L + (size_t)(p * 256 + wave * 64) * 8);
    }
  };
  auto stage_both = [&](int t, int buf) {
    int seg = t >> J.lgSteps;
    const unsigned short* Ab = (seg == 0) ? J.A0 : ((seg == 1) ? J.A1 : J.A2);
    size_t kof = (size_t)((t & kmask) << 6);
    stage(Ab + (size_t)bm * J.Astride + kof, J.Astride, &La[buf][0]);
    stage(J.Bt + (size_t)bn * J.Ktot + (size_t)t * 64, J.Ktot, &Lb[buf][0]);
  };

  stage_both(0, 0);
  __syncthreads();

  int cur = 0;
  for (int t = 0; t < nt; ++t) {
    if (t + 1 < nt) stage_both(t + 1, cur ^ 1);   // async DMA into other buffer
#pragma unroll
    for (int kc = 0; kc < 2; ++kc) {
      int kb = kc * 4 + lq;
      bf16x8 af[4], bv[4];
#pragma unroll
      for (int mi = 0; mi < 4; ++mi) {
        int r = wr + mi * 16 + lrow;
        af[mi] = *(const bf16x8*)&La[cur][r * 64 + ((kb + r) & 7) * 8];
      }
#pragma unroll
      for (int ni = 0; ni < 4; ++ni) {
        int r = wc + ni * 16 + lrow;
        bv[ni] = *(const bf16x8*)&Lb[cur][r * 64 + ((kb + r) & 7) * 8];
      }
#pragma unroll
      for (int mi = 0; mi < 4; ++mi)
#pragma unroll
        for (int ni = 0; ni < 4; ++ni)
          acc[mi][ni] = __builtin_amdgcn_mfma_f32_16x16x32_bf16(af[mi], bv[ni], acc[mi][ni], 0, 0, 0);
    }
    __syncthreads();   // drains prefetch DMA + publishes LDS
    cur ^= 1;
  }

  // epilogue: C/D layout col=lane&15, row=lq*4+reg
#pragma unroll
  for (int mi = 0; mi < 4; ++mi) {
#pragma unroll
    for (int ni = 0; ni < 4; ++ni) {
      int gn = bn + wc + ni * 16 + lrow;
      float bvs = J.bias[gn];
      int gm0 = bm + wr + mi * 16 + lq * 4;
      if (J.Cf) {
#pragma unroll
        for (int r = 0; r < 4; ++r)
          J.Cf[(size_t)(gm0 + r) * 512 + gn] = fmaxf(acc[mi][ni][r] + bvs, 0.f);
      } else {
#pragma unroll
        for (int r = 0; r < 4; ++r)
          J.Cb[(size_t)(gm0 + r) * 512 + gn] = f2bf(acc[mi][ni][r] + bvs);
      }
    }
  }
}

// ==== scores + separable softmax (all-bf16 inputs, direct global reads) ====
// Wsw[b,l,i] = softmax_i(cc * q . t_key[b,i]);  Wtw[b,l,j] = softmax_j(cc * q . s_key[b,j])
__global__ __launch_bounds__(256) void attn_scores(
    const unsigned short* __restrict__ qh, const unsigned short* __restrict__ s_key,
    const unsigned short* __restrict__ t_key, float* __restrict__ Wsw,
    float* __restrict__ Wtw) {
  int b = blockIdx.x, lc = blockIdx.y;
  int tid = threadIdx.x, wave = tid >> 6, lane = tid & 63;
  int lrow = lane & 15, lq = lane >> 4;
  int mat = wave >> 1, rh = wave & 1;
  int row0 = b * 128 + lc * 32 + rh * 16;
  const unsigned short* qp = qh + (size_t)row0 * 512;
  const unsigned short* key = (mat ? s_key : t_key) + (size_t)b * 36 * 512;
  float* W = (mat ? Wtw : Wsw);
  f32x4 acc[3] = {};
  for (int kc = 0; kc < 16; ++kc) {
    int k = kc * 32 + lq * 8;
    bf16x8 af = *(const bf16x8*)(qp + (size_t)lrow * 512 + k);
#pragma unroll
    for (int nf = 0; nf < 3; ++nf) {
      int n = nf * 16 + lrow; if (n > 35) n = 35;   // clamp; masked in softmax
      bf16x8 bv = *(const bf16x8*)(key + (size_t)n * 512 + k);
      acc[nf] = __builtin_amdgcn_mfma_f32_16x16x32_bf16(af, bv, acc[nf], 0, 0, 0);
    }
  }
  const float ccs = 0.022097086912079608f;   // 0.5 / sqrt(512)
  float ex[3][4];
#pragma unroll
  for (int r = 0; r < 4; ++r) {
    float a0 = acc[0][r] * ccs;
    float a1 = acc[1][r] * ccs;
    float a2 = (lrow < 4) ? acc[2][r] * ccs : -1e30f;
    float mx = fmaxf(fmaxf(a0, a1), a2);
    for (int s = 1; s < 16; s <<= 1) mx = fmaxf(mx, __shfl_xor(mx, s));
    float e0 = __expf(a0 - mx), e1 = __expf(a1 - mx);
    float e2 = (lrow < 4) ? __expf(a2 - mx) : 0.f;
    float sum = e0 + e1 + e2;
    for (int s = 1; s < 16; s <<= 1) sum += __shfl_xor(sum, s);
    float inv = 1.f / sum;
    ex[0][r] = e0 * inv; ex[1][r] = e1 * inv; ex[2][r] = e2 * inv;
  }
#pragma unroll
  for (int nf = 0; nf < 3; ++nf) {
    int col = nf * 16 + lrow;
    if (col < 36) {
#pragma unroll
      for (int r = 0; r < 4; ++r)
        W[(size_t)(row0 + lq * 4 + r) * 36 + col] = ex[nf][r];
    }
  }
}

// ==== ctx: ctx[l][h] = sum_j w[l][j] * V[j][h], K=36; output bf16 swizzled ==
__global__ __launch_bounds__(256) void attn_ctx(
    const float* __restrict__ Wsw, const float* __restrict__ Wtw,
    const unsigned short* __restrict__ s_val, const unsigned short* __restrict__ t_val,
    unsigned short* __restrict__ s_ctx, unsigned short* __restrict__ t_ctx) {
  __shared__ unsigned short vl[36 * 512];   // 36.9 KB
  __shared__ float wlT[36 * 32];            // [j][l], 4.6 KB
  int lc = blockIdx.x, mat = blockIdx.y, b = blockIdx.z;
  const unsigned short* V = (mat ? t_val : s_val) + (size_t)b * 36 * 512;
  const float* W = (mat ? Wtw : Wsw) + ((size_t)b * 128 + lc * 32) * 36;
  unsigned short* C = (mat ? t_ctx : s_ctx);
  int tid = threadIdx.x;
  for (int i = tid; i < 36 * 512 / 8; i += 256)
    *(bf16x8*)&vl[i * 8] = *(const bf16x8*)(V + (size_t)i * 8);
  for (int i = tid; i < 32 * 36; i += 256) {
    int l = i / 36, j = i - l * 36;
    wlT[j * 32 + l] = W[i];
  }
  __syncthreads();
  int lgrp = tid >> 6, hgrp = tid & 63;
  float acc[8][8] = {};
  for (int j = 0; j < 36; ++j) {
    f32x4 wa = *(const f32x4*)&wlT[j * 32 + lgrp * 8];       // broadcast
    f32x4 wb = *(const f32x4*)&wlT[j * 32 + lgrp * 8 + 4];
    bf16x8 v = *(const bf16x8*)&vl[j * 512 + hgrp * 8];      // contiguous 1KB/wave
    float vf[8];
#pragma unroll
    for (int hi = 0; hi < 8; ++hi) vf[hi] = bf2f((unsigned short)v[hi]);
#pragma unroll
    for (int li = 0; li < 4; ++li)
#pragma unroll
      for (int hi = 0; hi < 8; ++hi) acc[li][hi] += wa[li] * vf[hi];
#pragma unroll
    for (int li = 0; li < 4; ++li)
#pragma unroll
      for (int hi = 0; hi < 8; ++hi) acc[4 + li][hi] += wb[li] * vf[hi];
  }
  int kg = hgrp >> 3, kb = hgrp & 7;
#pragma unroll
  for (int li = 0; li < 8; ++li) {
    int R = b * 128 + lc * 32 + lgrp * 8 + li;
    int kswz = kg * 64 + ((kb + R) & 7) * 8;
    bf16x8 o;
#pragma unroll
    for (int hi = 0; hi < 8; ++hi) o[hi] = (short)f2bf(acc[li][hi]);
    *(bf16x8*)(C + (size_t)R * 512 + kswz) = o;
  }
}

// ---------------------------------------------------------------------------
extern "C" void kernel_launch(void* const* d_in, const int* in_sizes, int n_in,
                              void* d_out, int out_size, void* d_ws, size_t ws_size,
                              hipStream_t stream) {
  (void)in_sizes; (void)n_in; (void)out_size; (void)ws_size;
  const float* query = (const float*)d_in[0];
  const float* src   = (const float*)d_in[1];
  const float* trg   = (const float*)d_in[2];
  const float* Wq  = (const float*)d_in[3];  const float* bq  = (const float*)d_in[4];
  const float* Wsk = (const float*)d_in[5];  const float* bs  = (const float*)d_in[6];
  const float* Wtk = (const float*)d_in[7];  const float* bt  = (const float*)d_in[8];
  const float* Wsv = (const float*)d_in[9];  const float* bsv = (const float*)d_in[10];
  const float* Wtv = (const float*)d_in[11]; const float* btv = (const float*)d_in[12];
  const float* Wo  = (const float*)d_in[13]; const float* bo  = (const float*)d_in[14];

  // workspace (all bf16 shorts unless noted) ~42 MB
  unsigned short* WqT  = (unsigned short*)d_ws;       // 512*512
  unsigned short* WsT  = WqT  + 512 * 512;            // 512*2048 each
  unsigned short* WtT  = WsT  + 512 * 2048;
  unsigned short* WsvT = WtT  + 512 * 2048;
  unsigned short* WtvT = WsvT + 512 * 2048;
  unsigned short* WoT  = WtvT + 512 * 2048;           // 512*1536
  unsigned short* queryB = WoT + 512 * 1536;          // 4096*512 swz
  unsigned short* srcB   = queryB + 4096 * 512;       // 1152*2048 swz
  unsigned short* trgB   = srcB + 1152 * 2048;
  unsigned short* qh     = trgB + 1152 * 2048;        // 4096*512 (unswz)
  unsigned short* s_key  = qh + 4096 * 512;           // 1152*512 (unswz)
  unsigned short* t_key  = s_key + 1152 * 512;
  unsigned short* s_val  = t_key + 1152 * 512;
  unsigned short* t_val  = s_val + 1152 * 512;
  unsigned short* s_ctx  = t_val + 1152 * 512;        // 4096*512 swz
  unsigned short* t_ctx  = s_ctx + 4096 * 512;
  float* Wsw = (float*)(t_ctx + 4096 * 512);          // 4096*36 f32
  float* Wtw = Wsw + 4096 * 36;
  float* out = (float*)d_out;

  // 1. prep: 6 weight transposes + 3 activation converts, all bf16 swz
  PrepJobs pj;
  const float* psrc[9] = { Wq, Wsk, Wtk, Wsv, Wtv, Wo, query, src, trg };
  unsigned short* pdst[9] = { WqT, WsT, WtT, WsvT, WtvT, WoT, queryB, srcB, trgB };
  int pK[9]    = { 512, 2048, 2048, 2048, 2048, 1536, 512, 2048, 2048 };
  int ptype[9] = { 0, 0, 0, 0, 0, 0, 1, 1, 1 };
  int prows[9] = { 0, 0, 0, 0, 0, 0, 4096, 1152, 1152 };
  int pbase = 0;
  for (int i = 0; i < 9; ++i) {
    pj.src[i] = psrc[i]; pj.dst[i] = pdst[i]; pj.K[i] = pK[i]; pj.type[i] = ptype[i];
    pj.base[i] = pbase;
    pbase += ptype[i] ? (prows[i] / 64) * (pK[i] / 64) : (pK[i] / 32) * 16;
  }
  prep<<<pbase, 256, 0, stream>>>(pj);

  // 2. merged projections: 4x (1152x512,K=2048) + q (4096x512,K=512) = 272 blocks
  {
    GBatch pb;
    const unsigned short* Aarr[5] = { srcB, trgB, srcB, trgB, queryB };
    const unsigned short* Barr[5] = { WsT, WtT, WsvT, WtvT, WqT };
    const float* biasArr[5] = { bs, bt, bsv, btv, bq };
    unsigned short* Carr[5] = { s_key, t_key, s_val, t_val, qh };
    int base = 0;
    for (int i = 0; i < 5; ++i) {
      GJob& j = pb.j[i];
      j.A0 = Aarr[i]; j.A1 = Aarr[i]; j.A2 = Aarr[i];
      j.Bt = Barr[i]; j.bias = biasArr[i]; j.Cb = Carr[i]; j.Cf = nullptr;
      if (i < 4) { j.Astride = 2048; j.Ktot = 2048; j.lgSteps = 5; }
      else       { j.Astride = 512;  j.Ktot = 512;  j.lgSteps = 3; }
      j.tileBase = base;
      base += ((i < 4 ? 1152 : 4096) / 128) * 4;
    }
    pb.njobs = 5;
    gemm128<<<base, 256, 0, stream>>>(pb);   // 272 (div by 8)
  }

  // 3. separable scores + softmax (128 blocks)
  attn_scores<<<dim3(32, 4), 256, 0, stream>>>(qh, s_key, t_key, Wsw, Wtw);

  // 4. context weighted sums -> bf16 swizzled (256 blocks)
  attn_ctx<<<dim3(4, 2, 32), 256, 0, stream>>>(Wsw, Wtw, s_val, t_val, s_ctx, t_ctx);

  // 5. output GEMM on [queryB | s_ctx | t_ctx], bias + ReLU, f32 out (128 blocks)
  {
    GBatch ob;
    GJob& j = ob.j[0];
    j.A0 = queryB; j.A1 = s_ctx; j.A2 = t_ctx;
    j.Bt = WoT; j.bias = bo; j.Cb = nullptr; j.Cf = out;
    j.Astride = 512; j.Ktot = 1536; j.lgSteps = 3;
    j.tileBase = 0;
    for (int i = 1; i < 5; ++i) { ob.j[i] = j; ob.j[i].tileBase = 0x7fffffff; }
    ob.njobs = 1;
    gemm128<<<(4096 / 128) * 4, 256, 0, stream>>>(ob);
  }
}

// Round 4
// 97.246 us; speedup vs baseline: 3.0359x; 1.1185x over previous
//
#include <hip/hip_runtime.h>
#include <hip/hip_bf16.h>
#include <math.h>

#define DEVI __device__ __forceinline__

typedef __attribute__((ext_vector_type(4))) float f32x4;
typedef __attribute__((ext_vector_type(8))) short bf16x8;

DEVI unsigned short f2bf(float f) {
  union { float f; unsigned int u; } v; v.f = f;
  return (unsigned short)((v.u + 0x7FFFu + ((v.u >> 16) & 1u)) >> 16);
}
DEVI float bf2f(unsigned short s) {
  union { unsigned int u; float f; } v; v.u = ((unsigned int)s) << 16; return v.f;
}
DEVI bf16x8 pack8(f32x4 a, f32x4 b) {
  bf16x8 r;
  r[0] = (short)f2bf(a[0]); r[1] = (short)f2bf(a[1]);
  r[2] = (short)f2bf(a[2]); r[3] = (short)f2bf(a[3]);
  r[4] = (short)f2bf(b[0]); r[5] = (short)f2bf(b[1]);
  r[6] = (short)f2bf(b[2]); r[7] = (short)f2bf(b[3]);
  return r;
}
DEVI void gload16(const unsigned short* g, unsigned short* l) {
  __builtin_amdgcn_global_load_lds(
      (const __attribute__((address_space(1))) unsigned int*)g,
      (__attribute__((address_space(3))) unsigned int*)l, 16, 0, 0);
}
// raw workgroup barrier WITHOUT the implicit vmcnt(0) drain of __syncthreads
#define SBAR() do { asm volatile("" ::: "memory"); \
                    __builtin_amdgcn_s_barrier();  \
                    asm volatile("" ::: "memory"); } while (0)

// ==== prep: weights f32[K][512] -> bf16 [512][K] swz ; acts f32[M][K] -> bf16 [M][K] swz
// swizzle: within each 64-elem k-group, kblock kb of row n stored at ((kb+n)&7).
struct PrepJobs {
  const float* src[9];
  unsigned short* dst[9];
  int K[9];
  int base[9];
  int type[9];   // 0 = weight transpose, 1 = activation convert
};

__global__ __launch_bounds__(256) void prep(PrepJobs J) {
  __shared__ float t[32][33];
  int tile = blockIdx.x;
  int job = 0;
  while (job < 8 && tile >= J.base[job + 1]) ++job;
  int tl = tile - J.base[job];
  int K = J.K[job];
  if (J.type[job] == 0) {
    int tn = tl & 15, tk = tl >> 4;   // 512/32 = 16 n-tiles
    int x = threadIdx.x & 31, y = threadIdx.x >> 5;
    const float* s = J.src[job];
    int k0 = tk * 32, n0 = tn * 32;
    for (int yy = y; yy < 32; yy += 8)
      t[yy][x] = s[(size_t)(k0 + yy) * 512 + n0 + x];
    __syncthreads();
    unsigned short* d = J.dst[job];
    int k = k0 + x;
    int kg = k >> 6, kb = (k >> 3) & 7, ko = k & 7;
    for (int yy = y; yy < 32; yy += 8) {
      int n = n0 + yy;
      int kswz = (kg << 6) | (((kb + n) & 7) << 3) | ko;
      d[(size_t)n * K + kswz] = f2bf(t[x][yy]);
    }
  } else {
    int nk = K >> 6;
    int rt = tl / nk;
    int r0 = rt * 64, k0 = (tl - rt * nk) * 64;
    int r = threadIdx.x >> 2, kq = threadIdx.x & 3;
    int row = r0 + r;
    const float* s = J.src[job] + (size_t)row * K + k0 + kq * 16;
    f32x4 a0 = *(const f32x4*)s;
    f32x4 a1 = *(const f32x4*)(s + 4);
    f32x4 a2 = *(const f32x4*)(s + 8);
    f32x4 a3 = *(const f32x4*)(s + 12);
    unsigned short* d = J.dst[job] + (size_t)row * K + k0;
    int kb0 = kq * 2;
    *(bf16x8*)(d + ((kb0 + row) & 7) * 8) = pack8(a0, a1);
    *(bf16x8*)(d + ((kb0 + 1 + row) & 7) * 8) = pack8(a2, a3);
  }
}

// ==== MFMA GEMM, counted-vmcnt double-buffer pipeline, raw barriers ========
// C[M][512] = concat(A0|A1|A2) @ B + bias. BM = MI*32 (2 m-waves x wave tile
// (MI*16) x 64), BN = 128, BK = 64. A/B bf16 pre-swizzled; staging is pure
// global_load_lds DMA. s_waitcnt vmcnt(MI+4) per step -> next tile's loads
// stay in flight across the barrier (T3/T4-minimal).
struct GJob {
  const unsigned short* A0; const unsigned short* A1; const unsigned short* A2;
  const unsigned short* Bt;
  const float* bias;
  unsigned short* Cb;
  float* Cf;
  int Astride, Ktot, lgSteps, tileBase;
};
struct GBatch { GJob j[5]; int njobs; };

template <int MI>
__global__ __launch_bounds__(256) void gemm_pipe(GBatch batch) {
  constexpr int BM = MI * 32;
  // XCD-aware swizzle (grids divisible by 8)
  int cpx = gridDim.x >> 3;
  int gt = (blockIdx.x & 7) * cpx + (blockIdx.x >> 3);
  int job = 0;
#pragma unroll
  for (int i = 1; i < 5; ++i)
    if (i < batch.njobs && gt >= batch.j[i].tileBase) job = i;
  GJob J = batch.j[job];
  int tl = gt - J.tileBase;
  int bm = (tl >> 2) * BM, bn = (tl & 3) * 128;   // N=512 -> 4 n-tiles

  __shared__ __align__(16) unsigned short La[2][BM * 64];
  __shared__ __align__(16) unsigned short Lb[2][128 * 64];

  int tid = threadIdx.x;
  int wave = tid >> 6, lane = tid & 63;
  int lrow = lane & 15, lq = lane >> 4;
  int wr = (wave >> 1) * (MI * 16), wc = (wave & 1) * 64;
  f32x4 acc[MI][4] = {};

  int kmask = (1 << J.lgSteps) - 1;
  int nt = J.Ktot >> 6;

  auto stage_both = [&](int t, int buf) {
    int seg = t >> J.lgSteps;
    const unsigned short* Ab = (seg == 0) ? J.A0 : ((seg == 1) ? J.A1 : J.A2);
    const unsigned short* GA = Ab + (size_t)bm * J.Astride + (size_t)((t & kmask) << 6);
    const unsigned short* GB = J.Bt + (size_t)bn * J.Ktot + (size_t)t * 64;
#pragma unroll
    for (int p = 0; p < MI; ++p) {     // A: BM*64 bf16 = MI*256 slots of 16B
      int s = p * 256 + tid;
      gload16(GA + (size_t)(s >> 3) * J.Astride + (s & 7) * 8,
              &La[buf][(size_t)(p * 256 + wave * 64) * 8]);
    }
#pragma unroll
    for (int p = 0; p < 4; ++p) {      // B: 128*64 bf16 = 1024 slots
      int s = p * 256 + tid;
      gload16(GB + (size_t)(s >> 3) * J.Ktot + (s & 7) * 8,
              &Lb[buf][(size_t)(p * 256 + wave * 64) * 8]);
    }
  };

  stage_both(0, 0);
  if (nt > 1) stage_both(1, 1);

  for (int t = 0; t < nt; ++t) {
    // wait until THIS tile's DMA landed; next tile's (MI+4) may stay in flight
    if (t + 1 < nt) {
      if constexpr (MI == 4) asm volatile("s_waitcnt vmcnt(8)" ::: "memory");
      else                   asm volatile("s_waitcnt vmcnt(6)" ::: "memory");
    } else {
      asm volatile("s_waitcnt vmcnt(0)" ::: "memory");
    }
    SBAR();                              // all waves' tile-t data visible
    int cur = t & 1;
#pragma unroll
    for (int kc = 0; kc < 2; ++kc) {
      int kb = kc * 4 + lq;
      bf16x8 af[MI], bv[4];
#pragma unroll
      for (int mi = 0; mi < MI; ++mi) {
        int r = wr + mi * 16 + lrow;
        af[mi] = *(const bf16x8*)&La[cur][r * 64 + ((kb + r) & 7) * 8];
      }
#pragma unroll
      for (int ni = 0; ni < 4; ++ni) {
        int r = wc + ni * 16 + lrow;
        bv[ni] = *(const bf16x8*)&Lb[cur][r * 64 + ((kb + r) & 7) * 8];
      }
#pragma unroll
      for (int mi = 0; mi < MI; ++mi)
#pragma unroll
        for (int ni = 0; ni < 4; ++ni)
          acc[mi][ni] = __builtin_amdgcn_mfma_f32_16x16x32_bf16(af[mi], bv[ni], acc[mi][ni], 0, 0, 0);
    }
    SBAR();                              // all waves done reading buf[cur]
    if (t + 2 < nt) stage_both(t + 2, cur);   // refill freed buffer; lands during compute(t+1)
  }

  // epilogue: C/D layout col=lane&15, row=lq*4+reg
#pragma unroll
  for (int mi = 0; mi < MI; ++mi) {
#pragma unroll
    for (int ni = 0; ni < 4; ++ni) {
      int gn = bn + wc + ni * 16 + lrow;
      float bvs = J.bias[gn];
      int gm0 = bm + wr + mi * 16 + lq * 4;
      if (J.Cf) {
#pragma unroll
        for (int r = 0; r < 4; ++r)
          J.Cf[(size_t)(gm0 + r) * 512 + gn] = fmaxf(acc[mi][ni][r] + bvs, 0.f);
      } else {
#pragma unroll
        for (int r = 0; r < 4; ++r)
          J.Cb[(size_t)(gm0 + r) * 512 + gn] = f2bf(acc[mi][ni][r] + bvs);
      }
    }
  }
}

// ==== scores + separable softmax (all-bf16 inputs, direct global reads) ====
// Wsw[b,l,i] = softmax_i(cc * q . t_key[b,i]);  Wtw[b,l,j] = softmax_j(cc * q . s_key[b,j])
__global__ __launch_bounds__(256) void attn_scores(
    const unsigned short* __restrict__ qh, const unsigned short* __restrict__ s_key,
    const unsigned short* __restrict__ t_key, float* __restrict__ Wsw,
    float* __restrict__ Wtw) {
  int b = blockIdx.x, lc = blockIdx.y;
  int tid = threadIdx.x, wave = tid >> 6, lane = tid & 63;
  int lrow = lane & 15, lq = lane >> 4;
  int mat = wave >> 1, rh = wave & 1;
  int row0 = b * 128 + lc * 32 + rh * 16;
  const unsigned short* qp = qh + (size_t)row0 * 512;
  const unsigned short* key = (mat ? s_key : t_key) + (size_t)b * 36 * 512;
  float* W = (mat ? Wtw : Wsw);
  f32x4 acc[3] = {};
  for (int kc = 0; kc < 16; ++kc) {
    int k = kc * 32 + lq * 8;
    bf16x8 af = *(const bf16x8*)(qp + (size_t)lrow * 512 + k);
#pragma unroll
    for (int nf = 0; nf < 3; ++nf) {
      int n = nf * 16 + lrow; if (n > 35) n = 35;   // clamp; masked in softmax
      bf16x8 bv = *(const bf16x8*)(key + (size_t)n * 512 + k);
      acc[nf] = __builtin_amdgcn_mfma_f32_16x16x32_bf16(af, bv, acc[nf], 0, 0, 0);
    }
  }
  const float ccs = 0.022097086912079608f;   // 0.5 / sqrt(512)
  float ex[3][4];
#pragma unroll
  for (int r = 0; r < 4; ++r) {
    float a0 = acc[0][r] * ccs;
    float a1 = acc[1][r] * ccs;
    float a2 = (lrow < 4) ? acc[2][r] * ccs : -1e30f;
    float mx = fmaxf(fmaxf(a0, a1), a2);
    for (int s = 1; s < 16; s <<= 1) mx = fmaxf(mx, __shfl_xor(mx, s));
    float e0 = __expf(a0 - mx), e1 = __expf(a1 - mx);
    float e2 = (lrow < 4) ? __expf(a2 - mx) : 0.f;
    float sum = e0 + e1 + e2;
    for (int s = 1; s < 16; s <<= 1) sum += __shfl_xor(sum, s);
    float inv = 1.f / sum;
    ex[0][r] = e0 * inv; ex[1][r] = e1 * inv; ex[2][r] = e2 * inv;
  }
#pragma unroll
  for (int nf = 0; nf < 3; ++nf) {
    int col = nf * 16 + lrow;
    if (col < 36) {
#pragma unroll
      for (int r = 0; r < 4; ++r)
        W[(size_t)(row0 + lq * 4 + r) * 36 + col] = ex[nf][r];
    }
  }
}

// ==== ctx: ctx[l][h] = sum_j w[l][j] * V[j][h], K=36; output bf16 swizzled ==
__global__ __launch_bounds__(256) void attn_ctx(
    const float* __restrict__ Wsw, const float* __restrict__ Wtw,
    const unsigned short* __restrict__ s_val, const unsigned short* __restrict__ t_val,
    unsigned short* __restrict__ s_ctx, unsigned short* __restrict__ t_ctx) {
  __shared__ unsigned short vl[36 * 512];   // 36.9 KB
  __shared__ float wlT[36 * 32];            // [j][l], 4.6 KB
  int lc = blockIdx.x, mat = blockIdx.y, b = blockIdx.z;
  const unsigned short* V = (mat ? t_val : s_val) + (size_t)b * 36 * 512;
  const float* W = (mat ? Wtw : Wsw) + ((size_t)b * 128 + lc * 32) * 36;
  unsigned short* C = (mat ? t_ctx : s_ctx);
  int tid = threadIdx.x;
  for (int i = tid; i < 36 * 512 / 8; i += 256)
    *(bf16x8*)&vl[i * 8] = *(const bf16x8*)(V + (size_t)i * 8);
  for (int i = tid; i < 32 * 36; i += 256) {
    int l = i / 36, j = i - l * 36;
    wlT[j * 32 + l] = W[i];
  }
  __syncthreads();
  int lgrp = tid >> 6, hgrp = tid & 63;
  float acc[8][8] = {};
  for (int j = 0; j < 36; ++j) {
    f32x4 wa = *(const f32x4*)&wlT[j * 32 + lgrp * 8];       // broadcast
    f32x4 wb = *(const f32x4*)&wlT[j * 32 + lgrp * 8 + 4];
    bf16x8 v = *(const bf16x8*)&vl[j * 512 + hgrp * 8];      // contiguous 1KB/wave
    float vf[8];
#pragma unroll
    for (int hi = 0; hi < 8; ++hi) vf[hi] = bf2f((unsigned short)v[hi]);
#pragma unroll
    for (int li = 0; li < 4; ++li)
#pragma unroll
      for (int hi = 0; hi < 8; ++hi) acc[li][hi] += wa[li] * vf[hi];
#pragma unroll
    for (int li = 0; li < 4; ++li)
#pragma unroll
      for (int hi = 0; hi < 8; ++hi) acc[4 + li][hi] += wb[li] * vf[hi];
  }
  int kg = hgrp >> 3, kb = hgrp & 7;
#pragma unroll
  for (int li = 0; li < 8; ++li) {
    int R = b * 128 + lc * 32 + lgrp * 8 + li;
    int kswz = kg * 64 + ((kb + R) & 7) * 8;
    bf16x8 o;
#pragma unroll
    for (int hi = 0; hi < 8; ++hi) o[hi] = (short)f2bf(acc[li][hi]);
    *(bf16x8*)(C + (size_t)R * 512 + kswz) = o;
  }
}

// ---------------------------------------------------------------------------
extern "C" void kernel_launch(void* const* d_in, const int* in_sizes, int n_in,
                              void* d_out, int out_size, void* d_ws, size_t ws_size,
                              hipStream_t stream) {
  (void)in_sizes; (void)n_in; (void)out_size; (void)ws_size;
  const float* query = (const float*)d_in[0];
  const float* src   = (const float*)d_in[1];
  const float* trg   = (const float*)d_in[2];
  const float* Wq  = (const float*)d_in[3];  const float* bq  = (const float*)d_in[4];
  const float* Wsk = (const float*)d_in[5];  const float* bs  = (const float*)d_in[6];
  const float* Wtk = (const float*)d_in[7];  const float* bt  = (const float*)d_in[8];
  const float* Wsv = (const float*)d_in[9];  const float* bsv = (const float*)d_in[10];
  const float* Wtv = (const float*)d_in[11]; const float* btv = (const float*)d_in[12];
  const float* Wo  = (const float*)d_in[13]; const float* bo  = (const float*)d_in[14];

  // workspace (all bf16 shorts unless noted) ~42 MB
  unsigned short* WqT  = (unsigned short*)d_ws;       // 512*512
  unsigned short* WsT  = WqT  + 512 * 512;            // 512*2048 each
  unsigned short* WtT  = WsT  + 512 * 2048;
  unsigned short* WsvT = WtT  + 512 * 2048;
  unsigned short* WtvT = WsvT + 512 * 2048;
  unsigned short* WoT  = WtvT + 512 * 2048;           // 512*1536
  unsigned short* queryB = WoT + 512 * 1536;          // 4096*512 swz
  unsigned short* srcB   = queryB + 4096 * 512;       // 1152*2048 swz
  unsigned short* trgB   = srcB + 1152 * 2048;
  unsigned short* qh     = trgB + 1152 * 2048;        // 4096*512 (unswz)
  unsigned short* s_key  = qh + 4096 * 512;           // 1152*512 (unswz)
  unsigned short* t_key  = s_key + 1152 * 512;
  unsigned short* s_val  = t_key + 1152 * 512;
  unsigned short* t_val  = s_val + 1152 * 512;
  unsigned short* s_ctx  = t_val + 1152 * 512;        // 4096*512 swz
  unsigned short* t_ctx  = s_ctx + 4096 * 512;
  float* Wsw = (float*)(t_ctx + 4096 * 512);          // 4096*36 f32
  float* Wtw = Wsw + 4096 * 36;
  float* out = (float*)d_out;

  // 1. prep: 6 weight transposes + 3 activation converts, all bf16 swz
  PrepJobs pj;
  const float* psrc[9] = { Wq, Wsk, Wtk, Wsv, Wtv, Wo, query, src, trg };
  unsigned short* pdst[9] = { WqT, WsT, WtT, WsvT, WtvT, WoT, queryB, srcB, trgB };
  int pK[9]    = { 512, 2048, 2048, 2048, 2048, 1536, 512, 2048, 2048 };
  int ptype[9] = { 0, 0, 0, 0, 0, 0, 1, 1, 1 };
  int prows[9] = { 0, 0, 0, 0, 0, 0, 4096, 1152, 1152 };
  int pbase = 0;
  for (int i = 0; i < 9; ++i) {
    pj.src[i] = psrc[i]; pj.dst[i] = pdst[i]; pj.K[i] = pK[i]; pj.type[i] = ptype[i];
    pj.base[i] = pbase;
    pbase += ptype[i] ? (prows[i] / 64) * (pK[i] / 64) : (pK[i] / 32) * 16;
  }
  prep<<<pbase, 256, 0, stream>>>(pj);

  // 2. merged projections: 4x (1152x512,K=2048) + q (4096x512,K=512) = 272 blocks
  {
    GBatch pb;
    const unsigned short* Aarr[5] = { srcB, trgB, srcB, trgB, queryB };
    const unsigned short* Barr[5] = { WsT, WtT, WsvT, WtvT, WqT };
    const float* biasArr[5] = { bs, bt, bsv, btv, bq };
    unsigned short* Carr[5] = { s_key, t_key, s_val, t_val, qh };
    int base = 0;
    for (int i = 0; i < 5; ++i) {
      GJob& j = pb.j[i];
      j.A0 = Aarr[i]; j.A1 = Aarr[i]; j.A2 = Aarr[i];
      j.Bt = Barr[i]; j.bias = biasArr[i]; j.Cb = Carr[i]; j.Cf = nullptr;
      if (i < 4) { j.Astride = 2048; j.Ktot = 2048; j.lgSteps = 5; }
      else       { j.Astride = 512;  j.Ktot = 512;  j.lgSteps = 3; }
      j.tileBase = base;
      base += ((i < 4 ? 1152 : 4096) / 128) * 4;
    }
    pb.njobs = 5;
    gemm_pipe<4><<<base, 256, 0, stream>>>(pb);   // 272 blocks (div by 8)
  }

  // 3. separable scores + softmax (128 blocks)
  attn_scores<<<dim3(32, 4), 256, 0, stream>>>(qh, s_key, t_key, Wsw, Wtw);

  // 4. context weighted sums -> bf16 swizzled (256 blocks)
  attn_ctx<<<dim3(4, 2, 32), 256, 0, stream>>>(Wsw, Wtw, s_val, t_val, s_ctx, t_ctx);

  // 5. output GEMM on [queryB | s_ctx | t_ctx], BM=64 -> 256 blocks, f32+ReLU
  {
    GBatch ob;
    GJob& j = ob.j[0];
    j.A0 = queryB; j.A1 = s_ctx; j.A2 = t_ctx;
    j.Bt = WoT; j.bias = bo; j.Cb = nullptr; j.Cf = out;
    j.Astride = 512; j.Ktot = 1536; j.lgSteps = 3;
    j.tileBase = 0;
    for (int i = 1; i < 5; ++i) { ob.j[i] = j; ob.j[i].tileBase = 0x7fffffff; }
    ob.njobs = 1;
    gemm_pipe<2><<<(4096 / 64) * 4, 256, 0, stream>>>(ob);   // 256 blocks
  }
}

// Round 5
// 86.506 us; speedup vs baseline: 3.4128x; 1.1241x over previous
//
#include <hip/hip_runtime.h>
#include <hip/hip_bf16.h>
#include <math.h>

#define DEVI __device__ __forceinline__

typedef __attribute__((ext_vector_type(4))) float f32x4;
typedef __attribute__((ext_vector_type(8))) short bf16x8;

DEVI unsigned short f2bf(float f) {
  union { float f; unsigned int u; } v; v.f = f;
  return (unsigned short)((v.u + 0x7FFFu + ((v.u >> 16) & 1u)) >> 16);
}
DEVI float bf2f(unsigned short s) {
  union { unsigned int u; float f; } v; v.u = ((unsigned int)s) << 16; return v.f;
}
DEVI bf16x8 pack8(f32x4 a, f32x4 b) {
  bf16x8 r;
  r[0] = (short)f2bf(a[0]); r[1] = (short)f2bf(a[1]);
  r[2] = (short)f2bf(a[2]); r[3] = (short)f2bf(a[3]);
  r[4] = (short)f2bf(b[0]); r[5] = (short)f2bf(b[1]);
  r[6] = (short)f2bf(b[2]); r[7] = (short)f2bf(b[3]);
  return r;
}
DEVI void gload16(const unsigned short* g, unsigned short* l) {
  __builtin_amdgcn_global_load_lds(
      (const __attribute__((address_space(1))) unsigned int*)g,
      (__attribute__((address_space(3))) unsigned int*)l, 16, 0, 0);
}
// raw workgroup barrier WITHOUT the implicit vmcnt(0) drain of __syncthreads
#define SBAR() do { asm volatile("" ::: "memory"); \
                    __builtin_amdgcn_s_barrier();  \
                    asm volatile("" ::: "memory"); } while (0)

// ==== prep: weights f32[K][512] -> bf16 [512][K] swz ; acts f32[M][K] -> bf16 [M][K] swz
// swizzle: within each 64-elem k-group, kblock kb of row n stored at ((kb+n)&7).
struct PrepJobs {
  const float* src[9];
  unsigned short* dst[9];
  int K[9];
  int base[9];
  int type[9];   // 0 = weight transpose, 1 = activation convert
};

__global__ __launch_bounds__(256) void prep(PrepJobs J) {
  __shared__ float t[32][33];
  int tile = blockIdx.x;
  int job = 0;
  while (job < 8 && tile >= J.base[job + 1]) ++job;
  int tl = tile - J.base[job];
  int K = J.K[job];
  if (J.type[job] == 0) {
    int tn = tl & 15, tk = tl >> 4;   // 512/32 = 16 n-tiles
    int x = threadIdx.x & 31, y = threadIdx.x >> 5;
    const float* s = J.src[job];
    int k0 = tk * 32, n0 = tn * 32;
    for (int yy = y; yy < 32; yy += 8)
      t[yy][x] = s[(size_t)(k0 + yy) * 512 + n0 + x];
    __syncthreads();
    unsigned short* d = J.dst[job];
    int k = k0 + x;
    int kg = k >> 6, kb = (k >> 3) & 7, ko = k & 7;
    for (int yy = y; yy < 32; yy += 8) {
      int n = n0 + yy;
      int kswz = (kg << 6) | (((kb + n) & 7) << 3) | ko;
      d[(size_t)n * K + kswz] = f2bf(t[x][yy]);
    }
  } else {
    int nk = K >> 6;
    int rt = tl / nk;
    int r0 = rt * 64, k0 = (tl - rt * nk) * 64;
    int r = threadIdx.x >> 2, kq = threadIdx.x & 3;
    int row = r0 + r;
    const float* s = J.src[job] + (size_t)row * K + k0 + kq * 16;
    f32x4 a0 = *(const f32x4*)s;
    f32x4 a1 = *(const f32x4*)(s + 4);
    f32x4 a2 = *(const f32x4*)(s + 8);
    f32x4 a3 = *(const f32x4*)(s + 12);
    unsigned short* d = J.dst[job] + (size_t)row * K + k0;
    int kb0 = kq * 2;
    *(bf16x8*)(d + ((kb0 + row) & 7) * 8) = pack8(a0, a1);
    *(bf16x8*)(d + ((kb0 + 1 + row) & 7) * 8) = pack8(a2, a3);
  }
}

// ==== MFMA GEMM, counted-vmcnt double-buffer, templated tile ===============
// BM = MI*32, BN = NI*32, BK = 64; 4 waves (2 m x 2 n), wave tile (MI*16)x(NI*16).
// C[M][512] = concat(A0|A1|A2) @ B + bias. A/B bf16 pre-swizzled; staging is
// pure global_load_lds DMA; s_waitcnt vmcnt(MI+NI) keeps next tile in flight.
struct GJob {
  const unsigned short* A0; const unsigned short* A1; const unsigned short* A2;
  const unsigned short* Bt;
  const float* bias;
  unsigned short* Cb;
  float* Cf;
  int Astride, Ktot, lgSteps, tileBase;
};
struct GBatch { GJob j[5]; int njobs; };

template <int MI, int NI>
__global__ __launch_bounds__(256) void gemm_pipe(GBatch batch) {
  constexpr int BM = MI * 32, BN = NI * 32;
  constexpr int NT = 512 / BN;            // n-tiles per job
  // XCD-aware swizzle (grids divisible by 8)
  int cpx = gridDim.x >> 3;
  int gt = (blockIdx.x & 7) * cpx + (blockIdx.x >> 3);
  int job = 0;
#pragma unroll
  for (int i = 1; i < 5; ++i)
    if (i < batch.njobs && gt >= batch.j[i].tileBase) job = i;
  GJob J = batch.j[job];
  int tl = gt - J.tileBase;
  int bm = (tl / NT) * BM, bn = (tl % NT) * BN;

  __shared__ __align__(16) unsigned short La[2][BM * 64];
  __shared__ __align__(16) unsigned short Lb[2][BN * 64];

  int tid = threadIdx.x;
  int wave = tid >> 6, lane = tid & 63;
  int lrow = lane & 15, lq = lane >> 4;
  int wr = (wave >> 1) * (MI * 16), wc = (wave & 1) * (NI * 16);
  f32x4 acc[MI][NI] = {};

  int kmask = (1 << J.lgSteps) - 1;
  int nt = J.Ktot >> 6;

  auto stage_both = [&](int t, int buf) {
    int seg = t >> J.lgSteps;
    const unsigned short* Ab = (seg == 0) ? J.A0 : ((seg == 1) ? J.A1 : J.A2);
    const unsigned short* GA = Ab + (size_t)bm * J.Astride + (size_t)((t & kmask) << 6);
    const unsigned short* GB = J.Bt + (size_t)bn * J.Ktot + (size_t)t * 64;
#pragma unroll
    for (int p = 0; p < MI; ++p) {     // A: BM*64 bf16 = MI*256 slots of 16B
      int s = p * 256 + tid;
      gload16(GA + (size_t)(s >> 3) * J.Astride + (s & 7) * 8,
              &La[buf][(size_t)(p * 256 + wave * 64) * 8]);
    }
#pragma unroll
    for (int p = 0; p < NI; ++p) {     // B: BN*64 bf16 = NI*256 slots
      int s = p * 256 + tid;
      gload16(GB + (size_t)(s >> 3) * J.Ktot + (s & 7) * 8,
              &Lb[buf][(size_t)(p * 256 + wave * 64) * 8]);
    }
  };

  stage_both(0, 0);
  if (nt > 1) stage_both(1, 1);

  for (int t = 0; t < nt; ++t) {
    // wait until THIS tile's DMA landed; next tile's (MI+NI) stay in flight
    if (t + 1 < nt) {
      if constexpr (MI + NI == 8)      asm volatile("s_waitcnt vmcnt(8)" ::: "memory");
      else if constexpr (MI + NI == 6) asm volatile("s_waitcnt vmcnt(6)" ::: "memory");
      else                             asm volatile("s_waitcnt vmcnt(4)" ::: "memory");
    } else {
      asm volatile("s_waitcnt vmcnt(0)" ::: "memory");
    }
    SBAR();                              // all waves' tile-t data visible
    int cur = t & 1;
#pragma unroll
    for (int kc = 0; kc < 2; ++kc) {
      int kb = kc * 4 + lq;
      bf16x8 af[MI], bv[NI];
#pragma unroll
      for (int mi = 0; mi < MI; ++mi) {
        int r = wr + mi * 16 + lrow;
        af[mi] = *(const bf16x8*)&La[cur][r * 64 + ((kb + r) & 7) * 8];
      }
#pragma unroll
      for (int ni = 0; ni < NI; ++ni) {
        int r = wc + ni * 16 + lrow;
        bv[ni] = *(const bf16x8*)&Lb[cur][r * 64 + ((kb + r) & 7) * 8];
      }
#pragma unroll
      for (int mi = 0; mi < MI; ++mi)
#pragma unroll
        for (int ni = 0; ni < NI; ++ni)
          acc[mi][ni] = __builtin_amdgcn_mfma_f32_16x16x32_bf16(af[mi], bv[ni], acc[mi][ni], 0, 0, 0);
    }
    SBAR();                              // all waves done reading buf[cur]
    if (t + 2 < nt) stage_both(t + 2, cur);   // refill freed buffer
  }

  // epilogue: C/D layout col=lane&15, row=lq*4+reg
#pragma unroll
  for (int mi = 0; mi < MI; ++mi) {
#pragma unroll
    for (int ni = 0; ni < NI; ++ni) {
      int gn = bn + wc + ni * 16 + lrow;
      float bvs = J.bias[gn];
      int gm0 = bm + wr + mi * 16 + lq * 4;
      if (J.Cf) {
#pragma unroll
        for (int r = 0; r < 4; ++r)
          J.Cf[(size_t)(gm0 + r) * 512 + gn] = fmaxf(acc[mi][ni][r] + bvs, 0.f);
      } else {
#pragma unroll
        for (int r = 0; r < 4; ++r)
          J.Cb[(size_t)(gm0 + r) * 512 + gn] = f2bf(acc[mi][ni][r] + bvs);
      }
    }
  }
}

// ==== scores + separable softmax (all-bf16 inputs, direct global reads) ====
// Wsw[b,l,i] = softmax_i(cc * q . t_key[b,i]);  Wtw[b,l,j] = softmax_j(cc * q . s_key[b,j])
__global__ __launch_bounds__(256) void attn_scores(
    const unsigned short* __restrict__ qh, const unsigned short* __restrict__ s_key,
    const unsigned short* __restrict__ t_key, float* __restrict__ Wsw,
    float* __restrict__ Wtw) {
  int b = blockIdx.x, lc = blockIdx.y;
  int tid = threadIdx.x, wave = tid >> 6, lane = tid & 63;
  int lrow = lane & 15, lq = lane >> 4;
  int mat = wave >> 1, rh = wave & 1;
  int row0 = b * 128 + lc * 32 + rh * 16;
  const unsigned short* qp = qh + (size_t)row0 * 512;
  const unsigned short* key = (mat ? s_key : t_key) + (size_t)b * 36 * 512;
  float* W = (mat ? Wtw : Wsw);
  f32x4 acc[3] = {};
  for (int kc = 0; kc < 16; ++kc) {
    int k = kc * 32 + lq * 8;
    bf16x8 af = *(const bf16x8*)(qp + (size_t)lrow * 512 + k);
#pragma unroll
    for (int nf = 0; nf < 3; ++nf) {
      int n = nf * 16 + lrow; if (n > 35) n = 35;   // clamp; masked in softmax
      bf16x8 bv = *(const bf16x8*)(key + (size_t)n * 512 + k);
      acc[nf] = __builtin_amdgcn_mfma_f32_16x16x32_bf16(af, bv, acc[nf], 0, 0, 0);
    }
  }
  const float ccs = 0.022097086912079608f;   // 0.5 / sqrt(512)
  float ex[3][4];
#pragma unroll
  for (int r = 0; r < 4; ++r) {
    float a0 = acc[0][r] * ccs;
    float a1 = acc[1][r] * ccs;
    float a2 = (lrow < 4) ? acc[2][r] * ccs : -1e30f;
    float mx = fmaxf(fmaxf(a0, a1), a2);
    for (int s = 1; s < 16; s <<= 1) mx = fmaxf(mx, __shfl_xor(mx, s));
    float e0 = __expf(a0 - mx), e1 = __expf(a1 - mx);
    float e2 = (lrow < 4) ? __expf(a2 - mx) : 0.f;
    float sum = e0 + e1 + e2;
    for (int s = 1; s < 16; s <<= 1) sum += __shfl_xor(sum, s);
    float inv = 1.f / sum;
    ex[0][r] = e0 * inv; ex[1][r] = e1 * inv; ex[2][r] = e2 * inv;
  }
#pragma unroll
  for (int nf = 0; nf < 3; ++nf) {
    int col = nf * 16 + lrow;
    if (col < 36) {
#pragma unroll
      for (int r = 0; r < 4; ++r)
        W[(size_t)(row0 + lq * 4 + r) * 36 + col] = ex[nf][r];
    }
  }
}

// ==== ctx: ctx[l][h] = sum_j w[l][j] * V[j][h], K=36; output bf16 swizzled ==
__global__ __launch_bounds__(256) void attn_ctx(
    const float* __restrict__ Wsw, const float* __restrict__ Wtw,
    const unsigned short* __restrict__ s_val, const unsigned short* __restrict__ t_val,
    unsigned short* __restrict__ s_ctx, unsigned short* __restrict__ t_ctx) {
  __shared__ unsigned short vl[36 * 512];   // 36.9 KB
  __shared__ float wlT[36 * 32];            // [j][l], 4.6 KB
  int lc = blockIdx.x, mat = blockIdx.y, b = blockIdx.z;
  const unsigned short* V = (mat ? t_val : s_val) + (size_t)b * 36 * 512;
  const float* W = (mat ? Wtw : Wsw) + ((size_t)b * 128 + lc * 32) * 36;
  unsigned short* C = (mat ? t_ctx : s_ctx);
  int tid = threadIdx.x;
  for (int i = tid; i < 36 * 512 / 8; i += 256)
    *(bf16x8*)&vl[i * 8] = *(const bf16x8*)(V + (size_t)i * 8);
  for (int i = tid; i < 32 * 36; i += 256) {
    int l = i / 36, j = i - l * 36;
    wlT[j * 32 + l] = W[i];
  }
  __syncthreads();
  int lgrp = tid >> 6, hgrp = tid & 63;
  float acc[8][8] = {};
  for (int j = 0; j < 36; ++j) {
    f32x4 wa = *(const f32x4*)&wlT[j * 32 + lgrp * 8];       // broadcast
    f32x4 wb = *(const f32x4*)&wlT[j * 32 + lgrp * 8 + 4];
    bf16x8 v = *(const bf16x8*)&vl[j * 512 + hgrp * 8];      // contiguous 1KB/wave
    float vf[8];
#pragma unroll
    for (int hi = 0; hi < 8; ++hi) vf[hi] = bf2f((unsigned short)v[hi]);
#pragma unroll
    for (int li = 0; li < 4; ++li)
#pragma unroll
      for (int hi = 0; hi < 8; ++hi) acc[li][hi] += wa[li] * vf[hi];
#pragma unroll
    for (int li = 0; li < 4; ++li)
#pragma unroll
      for (int hi = 0; hi < 8; ++hi) acc[4 + li][hi] += wb[li] * vf[hi];
  }
  int kg = hgrp >> 3, kb = hgrp & 7;
#pragma unroll
  for (int li = 0; li < 8; ++li) {
    int R = b * 128 + lc * 32 + lgrp * 8 + li;
    int kswz = kg * 64 + ((kb + R) & 7) * 8;
    bf16x8 o;
#pragma unroll
    for (int hi = 0; hi < 8; ++hi) o[hi] = (short)f2bf(acc[li][hi]);
    *(bf16x8*)(C + (size_t)R * 512 + kswz) = o;
  }
}

// ---------------------------------------------------------------------------
extern "C" void kernel_launch(void* const* d_in, const int* in_sizes, int n_in,
                              void* d_out, int out_size, void* d_ws, size_t ws_size,
                              hipStream_t stream) {
  (void)in_sizes; (void)n_in; (void)out_size; (void)ws_size;
  const float* query = (const float*)d_in[0];
  const float* src   = (const float*)d_in[1];
  const float* trg   = (const float*)d_in[2];
  const float* Wq  = (const float*)d_in[3];  const float* bq  = (const float*)d_in[4];
  const float* Wsk = (const float*)d_in[5];  const float* bs  = (const float*)d_in[6];
  const float* Wtk = (const float*)d_in[7];  const float* bt  = (const float*)d_in[8];
  const float* Wsv = (const float*)d_in[9];  const float* bsv = (const float*)d_in[10];
  const float* Wtv = (const float*)d_in[11]; const float* btv = (const float*)d_in[12];
  const float* Wo  = (const float*)d_in[13]; const float* bo  = (const float*)d_in[14];

  // workspace (all bf16 shorts unless noted) ~42 MB
  unsigned short* WqT  = (unsigned short*)d_ws;       // 512*512
  unsigned short* WsT  = WqT  + 512 * 512;            // 512*2048 each
  unsigned short* WtT  = WsT  + 512 * 2048;
  unsigned short* WsvT = WtT  + 512 * 2048;
  unsigned short* WtvT = WsvT + 512 * 2048;
  unsigned short* WoT  = WtvT + 512 * 2048;           // 512*1536
  unsigned short* queryB = WoT + 512 * 1536;          // 4096*512 swz
  unsigned short* srcB   = queryB + 4096 * 512;       // 1152*2048 swz
  unsigned short* trgB   = srcB + 1152 * 2048;
  unsigned short* qh     = trgB + 1152 * 2048;        // 4096*512 (unswz)
  unsigned short* s_key  = qh + 4096 * 512;           // 1152*512 (unswz)
  unsigned short* t_key  = s_key + 1152 * 512;
  unsigned short* s_val  = t_key + 1152 * 512;
  unsigned short* t_val  = s_val + 1152 * 512;
  unsigned short* s_ctx  = t_val + 1152 * 512;        // 4096*512 swz
  unsigned short* t_ctx  = s_ctx + 4096 * 512;
  float* Wsw = (float*)(t_ctx + 4096 * 512);          // 4096*36 f32
  float* Wtw = Wsw + 4096 * 36;
  float* out = (float*)d_out;

  // 1. prep: 6 weight transposes + 3 activation converts, all bf16 swz
  PrepJobs pj;
  const float* psrc[9] = { Wq, Wsk, Wtk, Wsv, Wtv, Wo, query, src, trg };
  unsigned short* pdst[9] = { WqT, WsT, WtT, WsvT, WtvT, WoT, queryB, srcB, trgB };
  int pK[9]    = { 512, 2048, 2048, 2048, 2048, 1536, 512, 2048, 2048 };
  int ptype[9] = { 0, 0, 0, 0, 0, 0, 1, 1, 1 };
  int prows[9] = { 0, 0, 0, 0, 0, 0, 4096, 1152, 1152 };
  int pbase = 0;
  for (int i = 0; i < 9; ++i) {
    pj.src[i] = psrc[i]; pj.dst[i] = pdst[i]; pj.K[i] = pK[i]; pj.type[i] = ptype[i];
    pj.base[i] = pbase;
    pbase += ptype[i] ? (prows[i] / 64) * (pK[i] / 64) : (pK[i] / 32) * 16;
  }
  prep<<<pbase, 256, 0, stream>>>(pj);

  // 2. merged projections, BM=64/BN=128: 4x(18 m-tiles) + 64 m-tiles = 544 blocks
  {
    GBatch pb;
    const unsigned short* Aarr[5] = { srcB, trgB, srcB, trgB, queryB };
    const unsigned short* Barr[5] = { WsT, WtT, WsvT, WtvT, WqT };
    const float* biasArr[5] = { bs, bt, bsv, btv, bq };
    unsigned short* Carr[5] = { s_key, t_key, s_val, t_val, qh };
    int base = 0;
    for (int i = 0; i < 5; ++i) {
      GJob& j = pb.j[i];
      j.A0 = Aarr[i]; j.A1 = Aarr[i]; j.A2 = Aarr[i];
      j.Bt = Barr[i]; j.bias = biasArr[i]; j.Cb = Carr[i]; j.Cf = nullptr;
      if (i < 4) { j.Astride = 2048; j.Ktot = 2048; j.lgSteps = 5; }
      else       { j.Astride = 512;  j.Ktot = 512;  j.lgSteps = 3; }
      j.tileBase = base;
      base += ((i < 4 ? 1152 : 4096) / 64) * 4;   // NT = 4 at BN=128
    }
    pb.njobs = 5;
    gemm_pipe<2, 4><<<base, 256, 0, stream>>>(pb);   // 544 blocks (div by 8)
  }

  // 3. separable scores + softmax (128 blocks)
  attn_scores<<<dim3(32, 4), 256, 0, stream>>>(qh, s_key, t_key, Wsw, Wtw);

  // 4. context weighted sums -> bf16 swizzled (256 blocks)
  attn_ctx<<<dim3(4, 2, 32), 256, 0, stream>>>(Wsw, Wtw, s_val, t_val, s_ctx, t_ctx);

  // 5. output GEMM, BM=64/BN=64 -> 512 blocks, f32+ReLU
  {
    GBatch ob;
    GJob& j = ob.j[0];
    j.A0 = queryB; j.A1 = s_ctx; j.A2 = t_ctx;
    j.Bt = WoT; j.bias = bo; j.Cb = nullptr; j.Cf = out;
    j.Astride = 512; j.Ktot = 1536; j.lgSteps = 3;
    j.tileBase = 0;
    for (int i = 1; i < 5; ++i) { ob.j[i] = j; ob.j[i].tileBase = 0x7fffffff; }
    ob.njobs = 1;
    gemm_pipe<2, 2><<<(4096 / 64) * 8, 256, 0, stream>>>(ob);   // 512 blocks
  }
}